// Round 2
// baseline (1805.793 us; speedup 1.0000x reference)
//
#include <hip/hip_runtime.h>
#include <math.h>

#define CUTOFF 5.0f
#define H 64
#define FIN 16
#define NLAYERS 3

// 1/sqrt(1 + 1e-3)  (BN inference, moving mean 0 / var 1)
#define BN_INV 0.999500374750f

__device__ __forceinline__ float fast_tanh(float x) {
    x = fminf(fmaxf(x, -15.f), 15.f);
    float e = __expf(2.f * x);
    return (e - 1.f) / (e + 1.f);
}

__device__ __forceinline__ float softplus_f(float x) {
    // stable: max(x,0) + log1p(exp(-|x|))
    return fmaxf(x, 0.f) + __logf(1.f + __expf(-fabsf(x)));
}

// Precompute rowsum(fW2[l]) and sum(fb2[l]):  fs = cut*(sum_h t_h * wsum_h + bsum)
__global__ void k_wsum(const float* __restrict__ fW2, const float* __restrict__ fb2,
                       float* __restrict__ wsum, float* __restrict__ bsum) {
    int tid = threadIdx.x;
    if (tid < NLAYERS * H) {
        int l = tid >> 6, hh = tid & 63;
        float s = 0.f;
        for (int j = 0; j < H; j++) s += fW2[l * H * H + hh * H + j];
        wsum[tid] = s;
    }
    if (tid < NLAYERS) {
        float s = 0.f;
        for (int j = 0; j < H; j++) s += fb2[tid * H + j];
        bsum[tid] = s;
    }
}

// h = x @ emb_W + emb_b    (wave per node; lane = output channel)
__global__ void k_embed(const float* __restrict__ x, const float* __restrict__ emb_W,
                        const float* __restrict__ emb_b, float* __restrict__ h, int N) {
    int lane = threadIdx.x & 63;
    int w = threadIdx.x >> 6;
    int node = blockIdx.x * 4 + w;
    if (node >= N) return;
    float acc = emb_b[lane];
#pragma unroll
    for (int k = 0; k < FIN; k++) acc += x[node * FIN + k] * emb_W[k * H + lane];
    h[node * H + lane] = acc;
}

// Histogram of destination rows (counts into `cursor`, zeroed beforehand).
__global__ void k_hist(const int* __restrict__ ei, int* __restrict__ cnt, int E) {
    int e = blockIdx.x * blockDim.x + threadIdx.x;
    if (e < E) atomicAdd(&cnt[ei[e]], 1);
}

// Exclusive scan of counts -> row_ptr; also initializes cursor = starts.
// Single block of 256 threads; counts arrive in `cursor`, overwritten with starts.
__global__ void k_scan(int* __restrict__ cursor, int* __restrict__ row_ptr, int N) {
    __shared__ int s_part[256];
    int t = threadIdx.x;
    int chunk = (N + 255) / 256;
    int lo = t * chunk, hi = min(lo + chunk, N);
    int s = 0;
    for (int i = lo; i < hi; i++) s += cursor[i];
    s_part[t] = s;
    __syncthreads();
    for (int off = 1; off < 256; off <<= 1) {
        int v = (t >= off) ? s_part[t - off] : 0;
        __syncthreads();
        s_part[t] += v;
        __syncthreads();
    }
    int run = (t == 0) ? 0 : s_part[t - 1];
    for (int i = lo; i < hi; i++) {
        int c = cursor[i];
        row_ptr[i] = run;
        cursor[i] = run;
        run += c;
    }
    if (t == 255) row_ptr[N] = run;
}

// One wave per edge: compute fs for all 3 layers, then scatter (col, fs0..2)
// into row-sorted position via cursor.
__global__ void k_fs_scatter(const int* __restrict__ ei, const float* __restrict__ dist,
                             const float* __restrict__ fW1, const float* __restrict__ fb1,
                             const float* __restrict__ wsum, const float* __restrict__ bsum,
                             int* __restrict__ cursor, int* __restrict__ col_sorted,
                             float* __restrict__ fs_sorted, int E) {
    int lane = threadIdx.x & 63;
    int e = blockIdx.x * 4 + (threadIdx.x >> 6);
    if (e >= E) return;
    int row = ei[e], col = ei[E + e];
    float d = dist[e];
    float scaled = d * (2.0f / CUTOFF) - 1.0f;
    float cut = (d <= CUTOFF) ? 0.5f * (__cosf(d * (3.14159265358979f / CUTOFF)) + 1.0f)
                              : 0.0f;
    float fs0, fs1, fs2;
#pragma unroll
    for (int l = 0; l < NLAYERS; l++) {
        int wi = l * H + lane;
        float t = fast_tanh(scaled * fW1[wi] + fb1[wi]) * wsum[wi];
#pragma unroll
        for (int m = 32; m >= 1; m >>= 1) t += __shfl_xor(t, m, 64);
        float v = cut * (t + bsum[l]);
        if (l == 0) fs0 = v;
        else if (l == 1) fs1 = v;
        else fs2 = v;
    }
    if (lane == 0) {
        int pos = atomicAdd(&cursor[row], 1);
        col_sorted[pos] = col;
        fs_sorted[pos] = fs0;
        fs_sorted[(size_t)E + pos] = fs1;
        fs_sorted[2 * (size_t)E + pos] = fs2;
    }
}

// Fused per-layer kernel: CSR aggregation (no atomics) + node MLP + BN + residual.
// Block = 256 threads = 4 waves; block handles 64 nodes; wave handles 16 nodes.
// All LDS slices are wave-private -> no __syncthreads needed.
__global__ __launch_bounds__(256, 6)
void k_layer(const int* __restrict__ row_ptr, const int* __restrict__ col_sorted,
             const float* __restrict__ fs_sorted, const float* __restrict__ iW1,
             const float* __restrict__ ib1, const float* __restrict__ iW2,
             const float* __restrict__ ib2, const float* __restrict__ gamma,
             const float* __restrict__ beta, const float* __restrict__ h_in,
             float* __restrict__ h_out, int N, int E, int layer) {
    __shared__ float s_a[64][H];   // 16 KB, wave-private 16-row slices
    int lane = threadIdx.x & 63;
    int w = threadIdx.x >> 6;
    int base = blockIdx.x * 64 + w * 16;
    const float* fs = fs_sorted + (size_t)layer * E;

    // ---- aggregation ----
    for (int i = 0; i < 16; i++) {
        int node = __builtin_amdgcn_readfirstlane(base + i);
        float acc = 0.f;
        if (node < N) {
            int s = row_ptr[node], t = row_ptr[node + 1];
            for (int k = s; k < t; k++) {
                float fv = fs[k];
                int c = col_sorted[k];
                acc += fv * h_in[(size_t)c * H + lane];
            }
        }
        s_a[w * 16 + i][lane] = acc;
    }

    // ---- MLP layer 1: softplus(agg @ W1 + b1) ----
    const float* W1 = iW1 + layer * H * H;
    const float* W2 = iW2 + layer * H * H;
    float acc1[16];
    float b1 = ib1[layer * H + lane];
#pragma unroll
    for (int i = 0; i < 16; i++) acc1[i] = b1;
    for (int k = 0; k < H; k++) {
        float w1 = W1[k * H + lane];
#pragma unroll
        for (int i = 0; i < 16; i++) acc1[i] += s_a[w * 16 + i][k] * w1;
    }
#pragma unroll
    for (int i = 0; i < 16; i++) s_a[w * 16 + i][lane] = softplus_f(acc1[i]);

    // ---- MLP layer 2 + BN + residual ----
    float acc2[16];
    float b2 = ib2[layer * H + lane];
#pragma unroll
    for (int i = 0; i < 16; i++) acc2[i] = b2;
    for (int k = 0; k < H; k++) {
        float w2 = W2[k * H + lane];
#pragma unroll
        for (int i = 0; i < 16; i++) acc2[i] += s_a[w * 16 + i][k] * w2;
    }
    float g = gamma[layer * H + lane] * BN_INV;
    float b = beta[layer * H + lane];
#pragma unroll
    for (int i = 0; i < 16; i++) {
        int node = base + i;
        if (node < N) {
            float hv = h_in[(size_t)node * H + lane];
            h_out[(size_t)node * H + lane] = hv + acc2[i] * g + b;
        }
    }
}

// gsum[j] += sum over assigned nodes of h[i][j]
__global__ void k_mean(const float* __restrict__ h, float* __restrict__ gsum, int N) {
    __shared__ float s_r[4][H];
    int lane = threadIdx.x & 63;
    int w = threadIdx.x >> 6;
    int wg = blockIdx.x * 4 + w;
    int stride = gridDim.x * 4;
    float local = 0.f;
    for (int i = wg; i < N; i += stride) local += h[(size_t)i * H + lane];
    s_r[w][lane] = local;
    __syncthreads();
    if (w == 0) {
        float s = s_r[0][lane] + s_r[1][lane] + s_r[2][lane] + s_r[3][lane];
        atomicAdd(&gsum[lane], s);
    }
}

// Final tiny MLP chain on one block of 64 threads.
__global__ void k_final(const float* __restrict__ gsum, const float* __restrict__ oW1,
                        const float* __restrict__ ob1, const float* __restrict__ og1,
                        const float* __restrict__ obt1, const float* __restrict__ oW2,
                        const float* __restrict__ ob2, const float* __restrict__ og2,
                        const float* __restrict__ obt2, const float* __restrict__ fin_W,
                        const float* __restrict__ fin_b, float* __restrict__ out, int N) {
    __shared__ float sg[H], su[H / 2], sv[H / 2];
    int j = threadIdx.x;
    sg[j] = gsum[j] / (float)N;
    __syncthreads();
    if (j < H / 2) {
        float acc = ob1[j];
        for (int k = 0; k < H; k++) acc += sg[k] * oW1[k * (H / 2) + j];
        su[j] = softplus_f(acc) * BN_INV * og1[j] + obt1[j];
    }
    __syncthreads();
    if (j < H / 2) {
        float acc = ob2[j];
        for (int k = 0; k < H / 2; k++) acc += su[k] * oW2[k * (H / 2) + j];
        sv[j] = softplus_f(acc) * BN_INV * og2[j] + obt2[j];
    }
    __syncthreads();
    if (j < 3) {
        float acc = fin_b[j];
        for (int k = 0; k < H / 2; k++) acc += sv[k] * fin_W[k * 3 + j];
        out[j] = acc;
    }
}

extern "C" void kernel_launch(void* const* d_in, const int* in_sizes, int n_in,
                              void* d_out, int out_size, void* d_ws, size_t ws_size,
                              hipStream_t stream) {
    const float* x      = (const float*)d_in[0];
    const int*   ei     = (const int*)d_in[1];
    const float* dist   = (const float*)d_in[2];
    /* d_in[3] edge_attr: unused by reference */
    const float* emb_W  = (const float*)d_in[4];
    const float* emb_b  = (const float*)d_in[5];
    const float* fW1    = (const float*)d_in[6];
    const float* fb1    = (const float*)d_in[7];
    const float* fW2    = (const float*)d_in[8];
    const float* fb2    = (const float*)d_in[9];
    const float* iW1    = (const float*)d_in[10];
    const float* ib1    = (const float*)d_in[11];
    const float* iW2    = (const float*)d_in[12];
    const float* ib2    = (const float*)d_in[13];
    const float* bn_g   = (const float*)d_in[14];
    const float* bn_b   = (const float*)d_in[15];
    const float* oW1    = (const float*)d_in[16];
    const float* ob1    = (const float*)d_in[17];
    const float* og1    = (const float*)d_in[18];
    const float* obt1   = (const float*)d_in[19];
    const float* oW2    = (const float*)d_in[20];
    const float* ob2    = (const float*)d_in[21];
    const float* og2    = (const float*)d_in[22];
    const float* obt2   = (const float*)d_in[23];
    const float* fin_W  = (const float*)d_in[24];
    const float* fin_b  = (const float*)d_in[25];
    float* out = (float*)d_out;

    int N = in_sizes[0] / FIN;
    int E = in_sizes[2];

    // workspace layout (floats)
    float* ws        = (float*)d_ws;
    float* h0        = ws;                               // N*H
    float* h1        = h0 + (size_t)N * H;               // N*H
    float* fs_sorted = h1 + (size_t)N * H;               // 3*E
    float* wsum      = fs_sorted + (size_t)3 * E;        // L*H
    float* bsum      = wsum + NLAYERS * H;               // L (+pad to 8)
    float* gsum      = bsum + 8;                         // H
    int*   col_sorted = (int*)(gsum + H);                // E
    int*   row_ptr    = col_sorted + E;                  // N+1
    int*   cursor     = row_ptr + (N + 1);               // N

    hipMemsetAsync(gsum, 0, H * sizeof(float), stream);
    hipMemsetAsync(cursor, 0, N * sizeof(int), stream);

    k_wsum<<<1, 256, 0, stream>>>(fW2, fb2, wsum, bsum);

    int nb_node = (N + 3) / 4;
    k_embed<<<nb_node, 256, 0, stream>>>(x, emb_W, emb_b, h0, N);

    k_hist<<<(E + 255) / 256, 256, 0, stream>>>(ei, cursor, E);
    k_scan<<<1, 256, 0, stream>>>(cursor, row_ptr, N);

    int nb_edge = (E + 3) / 4;
    k_fs_scatter<<<nb_edge, 256, 0, stream>>>(ei, dist, fW1, fb1, wsum, bsum,
                                              cursor, col_sorted, fs_sorted, E);

    int nb_layer = (N + 63) / 64;
    float* hp[2] = {h0, h1};
    for (int l = 0; l < NLAYERS; l++) {
        k_layer<<<nb_layer, 256, 0, stream>>>(row_ptr, col_sorted, fs_sorted,
                                              iW1, ib1, iW2, ib2, bn_g, bn_b,
                                              hp[l & 1], hp[(l + 1) & 1], N, E, l);
    }
    float* h_final = hp[NLAYERS & 1];

    k_mean<<<1024, 256, 0, stream>>>(h_final, gsum, N);
    k_final<<<1, 64, 0, stream>>>(gsum, oW1, ob1, og1, obt1, oW2, ob2, og2, obt2,
                                  fin_W, fin_b, out, N);
}

// Round 3
// 1055.846 us; speedup vs baseline: 1.7103x; 1.7103x over previous
//
#include <hip/hip_runtime.h>
#include <math.h>

#define CUTOFF 5.0f
#define H 64
#define FIN 16
#define NLAYERS 3

// 1/sqrt(1 + 1e-3)  (BN inference, moving mean 0 / var 1)
#define BN_INV 0.999500374750f

__device__ __forceinline__ float fast_tanh(float x) {
    x = fminf(fmaxf(x, -15.f), 15.f);
    float e = __expf(2.f * x);
    return (e - 1.f) / (e + 1.f);
}

__device__ __forceinline__ float softplus_f(float x) {
    return fmaxf(x, 0.f) + __logf(1.f + __expf(-fabsf(x)));
}

// Precompute rowsum(fW2[l]) and sum(fb2[l]):  fs = cut*(sum_h t_h * wsum_h + bsum)
__global__ void k_wsum(const float* __restrict__ fW2, const float* __restrict__ fb2,
                       float* __restrict__ wsum, float* __restrict__ bsum) {
    int tid = threadIdx.x;
    if (tid < NLAYERS * H) {
        int l = tid >> 6, hh = tid & 63;
        float s = 0.f;
        for (int j = 0; j < H; j++) s += fW2[l * H * H + hh * H + j];
        wsum[tid] = s;
    }
    if (tid < NLAYERS) {
        float s = 0.f;
        for (int j = 0; j < H; j++) s += fb2[tid * H + j];
        bsum[tid] = s;
    }
}

// h = x @ emb_W + emb_b    (wave per node; lane = output channel)
__global__ void k_embed(const float* __restrict__ x, const float* __restrict__ emb_W,
                        const float* __restrict__ emb_b, float* __restrict__ h, int N) {
    int lane = threadIdx.x & 63;
    int w = threadIdx.x >> 6;
    int node = blockIdx.x * 4 + w;
    if (node >= N) return;
    float acc = emb_b[lane];
#pragma unroll
    for (int k = 0; k < FIN; k++) acc += x[node * FIN + k] * emb_W[k * H + lane];
    h[node * H + lane] = acc;
}

// Histogram of destination rows.
__global__ void k_hist(const int* __restrict__ ei, int* __restrict__ cnt, int E) {
    int e = blockIdx.x * blockDim.x + threadIdx.x;
    if (e < E) atomicAdd(&cnt[ei[e]], 1);
}

// Exclusive scan of counts -> row_ptr; also re-initializes cursor = starts.
__global__ void k_scan(int* __restrict__ cursor, int* __restrict__ row_ptr, int N) {
    __shared__ int s_part[256];
    int t = threadIdx.x;
    int chunk = (N + 255) / 256;
    int lo = t * chunk, hi = min(lo + chunk, N);
    int s = 0;
    for (int i = lo; i < hi; i++) s += cursor[i];
    s_part[t] = s;
    __syncthreads();
    for (int off = 1; off < 256; off <<= 1) {
        int v = (t >= off) ? s_part[t - off] : 0;
        __syncthreads();
        s_part[t] += v;
        __syncthreads();
    }
    int run = (t == 0) ? 0 : s_part[t - 1];
    for (int i = lo; i < hi; i++) {
        int c = cursor[i];
        row_ptr[i] = run;
        cursor[i] = run;
        run += c;
    }
    if (t == 255) row_ptr[N] = run;
}

// Thread-per-edge: compute fs for all 3 layers, write ONE float4 record
// {col, fs0, fs1, fs2} at the row-sorted position (single 16B store per edge;
// 64 independent atomic/scatter chains in flight per wave).
__global__ __launch_bounds__(256)
void k_fs_scatter(const int* __restrict__ ei, const float* __restrict__ dist,
                  const float* __restrict__ fW1, const float* __restrict__ fb1,
                  const float* __restrict__ wsum, const float* __restrict__ bsum,
                  int* __restrict__ cursor, float4* __restrict__ recs, int E) {
    int e = blockIdx.x * blockDim.x + threadIdx.x;
    if (e >= E) return;
    int row = ei[e], col = ei[E + e];
    float d = dist[e];
    float scaled = d * (2.0f / CUTOFF) - 1.0f;
    float cut = (d <= CUTOFF) ? 0.5f * (__cosf(d * (3.14159265358979f / CUTOFF)) + 1.0f)
                              : 0.0f;
    float fs[NLAYERS];
#pragma unroll
    for (int l = 0; l < NLAYERS; l++) {
        float s = 0.f;
#pragma unroll 8
        for (int hh = 0; hh < H; hh++) {
            int wi = l * H + hh;
            s += fast_tanh(scaled * fW1[wi] + fb1[wi]) * wsum[wi];
        }
        fs[l] = cut * (s + bsum[l]);
    }
    int pos = atomicAdd(&cursor[row], 1);
    recs[pos] = make_float4(__int_as_float(col), fs[0], fs[1], fs[2]);
}

// Fused per-layer kernel. One NODE per wave; lanes split into 4 groups of 16.
// Each group processes one edge/iteration: broadcast 16B record load + float4
// h-gather (group spans all 64 channels). Cross-group combine via shfl_xor,
// then the per-wave 64x64 MLP + BN + residual. Wave-private LDS, no barriers.
__global__ __launch_bounds__(256, 8)
void k_layer(const int* __restrict__ row_ptr, const float4* __restrict__ recs,
             const float* __restrict__ iW1, const float* __restrict__ ib1,
             const float* __restrict__ iW2, const float* __restrict__ ib2,
             const float* __restrict__ gamma, const float* __restrict__ beta,
             const float* __restrict__ h_in, float* __restrict__ h_out,
             int N, int layer) {
    __shared__ float s_a[4][H];
    int lane = threadIdx.x & 63;
    int w = threadIdx.x >> 6;
    int node = blockIdx.x * 4 + w;
    if (node >= N) return;
    int s = row_ptr[node], t = row_ptr[node + 1];
    int g = lane >> 4, ci = lane & 15;

    const float4* h4 = (const float4*)h_in;
    float4 acc = make_float4(0.f, 0.f, 0.f, 0.f);
    for (int k = s + g; k < t; k += 4) {
        float4 rec = recs[k];
        int c = __float_as_int(rec.x);
        float fv = (layer == 0) ? rec.y : (layer == 1) ? rec.z : rec.w;
        float4 hv = h4[(size_t)c * (H / 4) + ci];
        acc.x += fv * hv.x;
        acc.y += fv * hv.y;
        acc.z += fv * hv.z;
        acc.w += fv * hv.w;
    }
#pragma unroll
    for (int m = 16; m <= 32; m <<= 1) {
        acc.x += __shfl_xor(acc.x, m, 64);
        acc.y += __shfl_xor(acc.y, m, 64);
        acc.z += __shfl_xor(acc.z, m, 64);
        acc.w += __shfl_xor(acc.w, m, 64);
    }
    if (g == 0) ((float4*)s_a[w])[ci] = acc;   // wave-private; lgkmcnt handles hazard

    const float* W1 = iW1 + layer * H * H;
    const float* W2 = iW2 + layer * H * H;
    float acc1 = ib1[layer * H + lane];
#pragma unroll 8
    for (int k = 0; k < H; k++) acc1 += s_a[w][k] * W1[k * H + lane];
    float m1 = softplus_f(acc1);
    s_a[w][lane] = m1;
    float acc2 = ib2[layer * H + lane];
#pragma unroll 8
    for (int k = 0; k < H; k++) acc2 += s_a[w][k] * W2[k * H + lane];
    float out = acc2 * BN_INV * gamma[layer * H + lane] + beta[layer * H + lane];
    h_out[(size_t)node * H + lane] = h_in[(size_t)node * H + lane] + out;
}

// gsum[j] += sum over assigned nodes of h[i][j]
__global__ void k_mean(const float* __restrict__ h, float* __restrict__ gsum, int N) {
    __shared__ float s_r[4][H];
    int lane = threadIdx.x & 63;
    int w = threadIdx.x >> 6;
    int wg = blockIdx.x * 4 + w;
    int stride = gridDim.x * 4;
    float local = 0.f;
    for (int i = wg; i < N; i += stride) local += h[(size_t)i * H + lane];
    s_r[w][lane] = local;
    __syncthreads();
    if (w == 0) {
        float s = s_r[0][lane] + s_r[1][lane] + s_r[2][lane] + s_r[3][lane];
        atomicAdd(&gsum[lane], s);
    }
}

// Final tiny MLP chain on one block of 64 threads.
__global__ void k_final(const float* __restrict__ gsum, const float* __restrict__ oW1,
                        const float* __restrict__ ob1, const float* __restrict__ og1,
                        const float* __restrict__ obt1, const float* __restrict__ oW2,
                        const float* __restrict__ ob2, const float* __restrict__ og2,
                        const float* __restrict__ obt2, const float* __restrict__ fin_W,
                        const float* __restrict__ fin_b, float* __restrict__ out, int N) {
    __shared__ float sg[H], su[H / 2], sv[H / 2];
    int j = threadIdx.x;
    sg[j] = gsum[j] / (float)N;
    __syncthreads();
    if (j < H / 2) {
        float acc = ob1[j];
        for (int k = 0; k < H; k++) acc += sg[k] * oW1[k * (H / 2) + j];
        su[j] = softplus_f(acc) * BN_INV * og1[j] + obt1[j];
    }
    __syncthreads();
    if (j < H / 2) {
        float acc = ob2[j];
        for (int k = 0; k < H / 2; k++) acc += su[k] * oW2[k * (H / 2) + j];
        sv[j] = softplus_f(acc) * BN_INV * og2[j] + obt2[j];
    }
    __syncthreads();
    if (j < 3) {
        float acc = fin_b[j];
        for (int k = 0; k < H / 2; k++) acc += sv[k] * fin_W[k * 3 + j];
        out[j] = acc;
    }
}

extern "C" void kernel_launch(void* const* d_in, const int* in_sizes, int n_in,
                              void* d_out, int out_size, void* d_ws, size_t ws_size,
                              hipStream_t stream) {
    const float* x      = (const float*)d_in[0];
    const int*   ei     = (const int*)d_in[1];
    const float* dist   = (const float*)d_in[2];
    /* d_in[3] edge_attr: unused by reference */
    const float* emb_W  = (const float*)d_in[4];
    const float* emb_b  = (const float*)d_in[5];
    const float* fW1    = (const float*)d_in[6];
    const float* fb1    = (const float*)d_in[7];
    const float* fW2    = (const float*)d_in[8];
    const float* fb2    = (const float*)d_in[9];
    const float* iW1    = (const float*)d_in[10];
    const float* ib1    = (const float*)d_in[11];
    const float* iW2    = (const float*)d_in[12];
    const float* ib2    = (const float*)d_in[13];
    const float* bn_g   = (const float*)d_in[14];
    const float* bn_b   = (const float*)d_in[15];
    const float* oW1    = (const float*)d_in[16];
    const float* ob1    = (const float*)d_in[17];
    const float* og1    = (const float*)d_in[18];
    const float* obt1   = (const float*)d_in[19];
    const float* oW2    = (const float*)d_in[20];
    const float* ob2    = (const float*)d_in[21];
    const float* og2    = (const float*)d_in[22];
    const float* obt2   = (const float*)d_in[23];
    const float* fin_W  = (const float*)d_in[24];
    const float* fin_b  = (const float*)d_in[25];
    float* out = (float*)d_out;

    int N = in_sizes[0] / FIN;
    int E = in_sizes[2];

    // workspace layout (recs first for 16B alignment)
    float*  ws    = (float*)d_ws;
    float4* recs  = (float4*)ws;                         // E float4
    float*  h0    = ws + (size_t)4 * E;                  // N*H
    float*  h1    = h0 + (size_t)N * H;                  // N*H
    float*  wsum  = h1 + (size_t)N * H;                  // L*H
    float*  bsum  = wsum + NLAYERS * H;                  // L (+pad to 8)
    float*  gsum  = bsum + 8;                            // H
    int*    row_ptr = (int*)(gsum + H);                  // N+1
    int*    cursor  = row_ptr + (N + 1);                 // N

    hipMemsetAsync(gsum, 0, H * sizeof(float), stream);
    hipMemsetAsync(cursor, 0, N * sizeof(int), stream);

    k_wsum<<<1, 256, 0, stream>>>(fW2, fb2, wsum, bsum);

    int nb_node = (N + 3) / 4;
    k_embed<<<nb_node, 256, 0, stream>>>(x, emb_W, emb_b, h0, N);

    k_hist<<<(E + 255) / 256, 256, 0, stream>>>(ei, cursor, E);
    k_scan<<<1, 256, 0, stream>>>(cursor, row_ptr, N);

    k_fs_scatter<<<(E + 255) / 256, 256, 0, stream>>>(ei, dist, fW1, fb1, wsum, bsum,
                                                      cursor, recs, E);

    float* hp[2] = {h0, h1};
    for (int l = 0; l < NLAYERS; l++) {
        k_layer<<<nb_node, 256, 0, stream>>>(row_ptr, recs, iW1, ib1, iW2, ib2,
                                             bn_g, bn_b, hp[l & 1], hp[(l + 1) & 1],
                                             N, l);
    }
    float* h_final = hp[NLAYERS & 1];

    k_mean<<<1024, 256, 0, stream>>>(h_final, gsum, N);
    k_final<<<1, 64, 0, stream>>>(gsum, oW1, ob1, og1, obt1, oW2, ob2, og2, obt2,
                                  fin_W, fin_b, out, N);
}

// Round 4
// 810.447 us; speedup vs baseline: 2.2281x; 1.3028x over previous
//
#include <hip/hip_runtime.h>
#include <math.h>

#define CUTOFF 5.0f
#define H 64
#define FIN 16
#define NLAYERS 3

// 1/sqrt(1 + 1e-3)  (BN inference, moving mean 0 / var 1)
#define BN_INV 0.999500374750f

__device__ __forceinline__ float fast_tanh(float x) {
    x = fminf(fmaxf(x, -15.f), 15.f);
    float e = __expf(2.f * x);
    return (e - 1.f) / (e + 1.f);
}

__device__ __forceinline__ float softplus_f(float x) {
    return fmaxf(x, 0.f) + __logf(1.f + __expf(-fabsf(x)));
}

// Precompute rowsum(fW2[l]) and sum(fb2[l]):  fs = cut*(sum_h t_h * wsum_h + bsum)
__global__ void k_wsum(const float* __restrict__ fW2, const float* __restrict__ fb2,
                       float* __restrict__ wsum, float* __restrict__ bsum) {
    int tid = threadIdx.x;
    if (tid < NLAYERS * H) {
        int l = tid >> 6, hh = tid & 63;
        float s = 0.f;
        for (int j = 0; j < H; j++) s += fW2[l * H * H + hh * H + j];
        wsum[tid] = s;
    }
    if (tid < NLAYERS) {
        float s = 0.f;
        for (int j = 0; j < H; j++) s += fb2[tid * H + j];
        bsum[tid] = s;
    }
}

// h = x @ emb_W + emb_b    (wave per node; lane = output channel)
__global__ void k_embed(const float* __restrict__ x, const float* __restrict__ emb_W,
                        const float* __restrict__ emb_b, float* __restrict__ h, int N) {
    int lane = threadIdx.x & 63;
    int w = threadIdx.x >> 6;
    int node = blockIdx.x * 4 + w;
    if (node >= N) return;
    float acc = emb_b[lane];
#pragma unroll
    for (int k = 0; k < FIN; k++) acc += x[node * FIN + k] * emb_W[k * H + lane];
    h[node * H + lane] = acc;
}

// Histogram of destination rows.
__global__ void k_hist(const int* __restrict__ ei, int* __restrict__ cnt, int E) {
    int e = blockIdx.x * blockDim.x + threadIdx.x;
    if (e < E) atomicAdd(&cnt[ei[e]], 1);
}

// ---- hierarchical exclusive scan of cursor[N] -> row_ptr[N+1], cursor=starts ----
// scan1: per-block (256-wide) reduction of counts -> bsums[b]
__global__ void k_scan1(const int* __restrict__ cnt, int* __restrict__ bsums, int N) {
    __shared__ int sd[256];
    int i = blockIdx.x * 256 + threadIdx.x;
    sd[threadIdx.x] = (i < N) ? cnt[i] : 0;
    __syncthreads();
    for (int off = 128; off > 0; off >>= 1) {
        if (threadIdx.x < off) sd[threadIdx.x] += sd[threadIdx.x + off];
        __syncthreads();
    }
    if (threadIdx.x == 0) bsums[blockIdx.x] = sd[0];
}

// scan2: single block — exclusive scan of nb block sums in place
__global__ void k_scan2(int* __restrict__ bsums, int nb) {
    __shared__ int sp[256];
    int t = threadIdx.x;
    int chunk = (nb + 255) / 256;
    int lo = t * chunk, hi = min(lo + chunk, nb);
    int s = 0;
    for (int i = lo; i < hi; i++) s += bsums[i];
    sp[t] = s;
    __syncthreads();
    for (int off = 1; off < 256; off <<= 1) {
        int v = (t >= off) ? sp[t - off] : 0;
        __syncthreads();
        sp[t] += v;
        __syncthreads();
    }
    int run = (t == 0) ? 0 : sp[t - 1];
    for (int i = lo; i < hi; i++) {
        int c = bsums[i];
        bsums[i] = run;
        run += c;
    }
}

// scan3: per-block exclusive scan + block offset; writes row_ptr and cursor
__global__ void k_scan3(int* __restrict__ cursor, const int* __restrict__ bsums,
                        int* __restrict__ row_ptr, int N) {
    __shared__ int sd[256];
    int b = blockIdx.x;
    int i = b * 256 + threadIdx.x;
    int v = (i < N) ? cursor[i] : 0;
    sd[threadIdx.x] = v;
    __syncthreads();
    for (int off = 1; off < 256; off <<= 1) {
        int u = (threadIdx.x >= off) ? sd[threadIdx.x - off] : 0;
        __syncthreads();
        sd[threadIdx.x] += u;
        __syncthreads();
    }
    int excl = sd[threadIdx.x] - v + bsums[b];
    if (i < N) {
        row_ptr[i] = excl;
        cursor[i] = excl;
        if (i == N - 1) row_ptr[N] = excl + v;
    }
}

// Thread-per-edge: compute fs for all 3 layers, write ONE float4 record
// {col, fs0, fs1, fs2} at the row-sorted position.
__global__ __launch_bounds__(256)
void k_fs_scatter(const int* __restrict__ ei, const float* __restrict__ dist,
                  const float* __restrict__ fW1, const float* __restrict__ fb1,
                  const float* __restrict__ wsum, const float* __restrict__ bsum,
                  int* __restrict__ cursor, float4* __restrict__ recs, int E) {
    int e = blockIdx.x * blockDim.x + threadIdx.x;
    if (e >= E) return;
    int row = ei[e], col = ei[E + e];
    float d = dist[e];
    float scaled = d * (2.0f / CUTOFF) - 1.0f;
    float cut = (d <= CUTOFF) ? 0.5f * (__cosf(d * (3.14159265358979f / CUTOFF)) + 1.0f)
                              : 0.0f;
    float fs[NLAYERS];
#pragma unroll
    for (int l = 0; l < NLAYERS; l++) {
        float s = 0.f;
#pragma unroll 8
        for (int hh = 0; hh < H; hh++) {
            int wi = l * H + hh;
            s += fast_tanh(scaled * fW1[wi] + fb1[wi]) * wsum[wi];
        }
        fs[l] = cut * (s + bsum[l]);
    }
    int pos = atomicAdd(&cursor[row], 1);
    recs[pos] = make_float4(__int_as_float(col), fs[0], fs[1], fs[2]);
}

// Fused per-layer kernel. One NODE per wave; 8 groups of 8 lanes -> 8 edges in
// flight per wave; each lane gathers 2 float4 (channels 4ci..4ci+3 and 32+4ci..).
// Cross-group combine via shfl_xor; then per-wave 64x64 MLP + BN + residual.
__global__ __launch_bounds__(256)
void k_layer(const int* __restrict__ row_ptr, const float4* __restrict__ recs,
             const float* __restrict__ iW1, const float* __restrict__ ib1,
             const float* __restrict__ iW2, const float* __restrict__ ib2,
             const float* __restrict__ gamma, const float* __restrict__ beta,
             const float* __restrict__ h_in, float* __restrict__ h_out,
             int N, int layer) {
    __shared__ float s_a[4][H];
    int lane = threadIdx.x & 63;
    int w = threadIdx.x >> 6;
    int node = blockIdx.x * 4 + w;
    if (node >= N) return;
    int s = row_ptr[node], t = row_ptr[node + 1];
    int g = lane >> 3, ci = lane & 7;     // 8 groups x 8 lanes

    const float4* h4 = (const float4*)h_in;
    float4 aL = make_float4(0.f, 0.f, 0.f, 0.f);
    float4 aH = make_float4(0.f, 0.f, 0.f, 0.f);
    for (int k = s + g; k < t; k += 8) {
        float4 rec = recs[k];
        int c = __float_as_int(rec.x);
        float fv = (layer == 0) ? rec.y : (layer == 1) ? rec.z : rec.w;
        float4 hL = h4[(size_t)c * 16 + ci];
        float4 hH = h4[(size_t)c * 16 + 8 + ci];
        aL.x += fv * hL.x; aL.y += fv * hL.y; aL.z += fv * hL.z; aL.w += fv * hL.w;
        aH.x += fv * hH.x; aH.y += fv * hH.y; aH.z += fv * hH.z; aH.w += fv * hH.w;
    }
#pragma unroll
    for (int m = 8; m <= 32; m <<= 1) {
        aL.x += __shfl_xor(aL.x, m, 64); aL.y += __shfl_xor(aL.y, m, 64);
        aL.z += __shfl_xor(aL.z, m, 64); aL.w += __shfl_xor(aL.w, m, 64);
        aH.x += __shfl_xor(aH.x, m, 64); aH.y += __shfl_xor(aH.y, m, 64);
        aH.z += __shfl_xor(aH.z, m, 64); aH.w += __shfl_xor(aH.w, m, 64);
    }
    if (g == 0) {
        ((float4*)s_a[w])[ci] = aL;
        ((float4*)s_a[w])[8 + ci] = aH;
    }

    const float* W1 = iW1 + layer * H * H;
    const float* W2 = iW2 + layer * H * H;
    float acc1 = ib1[layer * H + lane];
#pragma unroll 8
    for (int k = 0; k < H; k++) acc1 += s_a[w][k] * W1[k * H + lane];
    float m1 = softplus_f(acc1);
    s_a[w][lane] = m1;
    float acc2 = ib2[layer * H + lane];
#pragma unroll 8
    for (int k = 0; k < H; k++) acc2 += s_a[w][k] * W2[k * H + lane];
    float out = acc2 * BN_INV * gamma[layer * H + lane] + beta[layer * H + lane];
    h_out[(size_t)node * H + lane] = h_in[(size_t)node * H + lane] + out;
}

// gsum[j] += sum over assigned nodes of h[i][j]
__global__ void k_mean(const float* __restrict__ h, float* __restrict__ gsum, int N) {
    __shared__ float s_r[4][H];
    int lane = threadIdx.x & 63;
    int w = threadIdx.x >> 6;
    int wg = blockIdx.x * 4 + w;
    int stride = gridDim.x * 4;
    float local = 0.f;
    for (int i = wg; i < N; i += stride) local += h[(size_t)i * H + lane];
    s_r[w][lane] = local;
    __syncthreads();
    if (w == 0) {
        float s = s_r[0][lane] + s_r[1][lane] + s_r[2][lane] + s_r[3][lane];
        atomicAdd(&gsum[lane], s);
    }
}

// Final tiny MLP chain on one block of 64 threads.
__global__ void k_final(const float* __restrict__ gsum, const float* __restrict__ oW1,
                        const float* __restrict__ ob1, const float* __restrict__ og1,
                        const float* __restrict__ obt1, const float* __restrict__ oW2,
                        const float* __restrict__ ob2, const float* __restrict__ og2,
                        const float* __restrict__ obt2, const float* __restrict__ fin_W,
                        const float* __restrict__ fin_b, float* __restrict__ out, int N) {
    __shared__ float sg[H], su[H / 2], sv[H / 2];
    int j = threadIdx.x;
    sg[j] = gsum[j] / (float)N;
    __syncthreads();
    if (j < H / 2) {
        float acc = ob1[j];
        for (int k = 0; k < H; k++) acc += sg[k] * oW1[k * (H / 2) + j];
        su[j] = softplus_f(acc) * BN_INV * og1[j] + obt1[j];
    }
    __syncthreads();
    if (j < H / 2) {
        float acc = ob2[j];
        for (int k = 0; k < H / 2; k++) acc += su[k] * oW2[k * (H / 2) + j];
        sv[j] = softplus_f(acc) * BN_INV * og2[j] + obt2[j];
    }
    __syncthreads();
    if (j < 3) {
        float acc = fin_b[j];
        for (int k = 0; k < H / 2; k++) acc += sv[k] * fin_W[k * 3 + j];
        out[j] = acc;
    }
}

extern "C" void kernel_launch(void* const* d_in, const int* in_sizes, int n_in,
                              void* d_out, int out_size, void* d_ws, size_t ws_size,
                              hipStream_t stream) {
    const float* x      = (const float*)d_in[0];
    const int*   ei     = (const int*)d_in[1];
    const float* dist   = (const float*)d_in[2];
    /* d_in[3] edge_attr: unused by reference */
    const float* emb_W  = (const float*)d_in[4];
    const float* emb_b  = (const float*)d_in[5];
    const float* fW1    = (const float*)d_in[6];
    const float* fb1    = (const float*)d_in[7];
    const float* fW2    = (const float*)d_in[8];
    const float* fb2    = (const float*)d_in[9];
    const float* iW1    = (const float*)d_in[10];
    const float* ib1    = (const float*)d_in[11];
    const float* iW2    = (const float*)d_in[12];
    const float* ib2    = (const float*)d_in[13];
    const float* bn_g   = (const float*)d_in[14];
    const float* bn_b   = (const float*)d_in[15];
    const float* oW1    = (const float*)d_in[16];
    const float* ob1    = (const float*)d_in[17];
    const float* og1    = (const float*)d_in[18];
    const float* obt1   = (const float*)d_in[19];
    const float* oW2    = (const float*)d_in[20];
    const float* ob2    = (const float*)d_in[21];
    const float* og2    = (const float*)d_in[22];
    const float* obt2   = (const float*)d_in[23];
    const float* fin_W  = (const float*)d_in[24];
    const float* fin_b  = (const float*)d_in[25];
    float* out = (float*)d_out;

    int N = in_sizes[0] / FIN;
    int E = in_sizes[2];
    int nb_scan = (N + 255) / 256;

    // workspace layout (recs first for 16B alignment)
    float*  ws    = (float*)d_ws;
    float4* recs  = (float4*)ws;                         // E float4
    float*  h0    = ws + (size_t)4 * E;                  // N*H
    float*  h1    = h0 + (size_t)N * H;                  // N*H
    float*  wsum  = h1 + (size_t)N * H;                  // L*H
    float*  bsum  = wsum + NLAYERS * H;                  // L (+pad to 8)
    float*  gsum  = bsum + 8;                            // H
    int*    row_ptr = (int*)(gsum + H);                  // N+1
    int*    cursor  = row_ptr + (N + 1);                 // N
    int*    bsums   = cursor + N;                        // nb_scan

    hipMemsetAsync(gsum, 0, H * sizeof(float), stream);
    hipMemsetAsync(cursor, 0, N * sizeof(int), stream);

    k_wsum<<<1, 256, 0, stream>>>(fW2, fb2, wsum, bsum);

    int nb_node = (N + 3) / 4;
    k_embed<<<nb_node, 256, 0, stream>>>(x, emb_W, emb_b, h0, N);

    k_hist<<<(E + 255) / 256, 256, 0, stream>>>(ei, cursor, E);
    k_scan1<<<nb_scan, 256, 0, stream>>>(cursor, bsums, N);
    k_scan2<<<1, 256, 0, stream>>>(bsums, nb_scan);
    k_scan3<<<nb_scan, 256, 0, stream>>>(cursor, bsums, row_ptr, N);

    k_fs_scatter<<<(E + 255) / 256, 256, 0, stream>>>(ei, dist, fW1, fb1, wsum, bsum,
                                                      cursor, recs, E);

    float* hp[2] = {h0, h1};
    for (int l = 0; l < NLAYERS; l++) {
        k_layer<<<nb_node, 256, 0, stream>>>(row_ptr, recs, iW1, ib1, iW2, ib2,
                                             bn_g, bn_b, hp[l & 1], hp[(l + 1) & 1],
                                             N, l);
    }
    float* h_final = hp[NLAYERS & 1];

    k_mean<<<1024, 256, 0, stream>>>(h_final, gsum, N);
    k_final<<<1, 64, 0, stream>>>(gsum, oW1, ob1, og1, obt1, oW2, ob2, og2, obt2,
                                  fin_W, fin_b, out, N);
}